// Round 14
// baseline (611.583 us; speedup 1.0000x reference)
//
#include <hip/hip_runtime.h>
#include <hip/hip_bf16.h>

#define D 64
#define BSZ 512              // nodes per bucket (window ~786KB)
#define EPB 4096             // edges per partition block

typedef unsigned short u16;
typedef unsigned long long u64;
typedef __attribute__((ext_vector_type(8))) unsigned short u16x8;
typedef __attribute__((ext_vector_type(8))) short bf16x8;
typedef __attribute__((ext_vector_type(4))) float f32x4;

static __device__ __forceinline__ u16 f2bf(float f) {
    unsigned u = __float_as_uint(f);
    unsigned r = (u + 0x7FFFu + ((u >> 16) & 1u)) >> 16;   // RNE
    return (u16)r;
}
static __device__ __forceinline__ float bf2f(u16 h) {
    return __uint_as_float(((unsigned)h) << 16);
}

// ---------------------------------------------------------------------------
__global__ void out_init_kernel(float* __restrict__ out, const float* __restrict__ bout, int G) {
    int i = blockIdx.x * blockDim.x + threadIdx.x;
    if (i < G) out[i] = bout[0];
}

// ---------------------------------------------------------------------------
// CSR build: histogram -> scan
// ---------------------------------------------------------------------------
__global__ void deg_hist_kernel(const int* __restrict__ ei, int* __restrict__ deg, int E) {
    int e = blockIdx.x * blockDim.x + threadIdx.x;
    if (e < E) atomicAdd(&deg[ei[E + e]], 1);
}

__global__ __launch_bounds__(1024) void scan1_kernel(
    const int* __restrict__ deg, int* __restrict__ off, int* __restrict__ bsum, int N)
{
    __shared__ int sh[1024];
    int t = threadIdx.x;
    int i = blockIdx.x * 1024 + t;
    int v = (i < N) ? deg[i] : 0;
    sh[t] = v;
    __syncthreads();
#pragma unroll
    for (int o = 1; o < 1024; o <<= 1) {
        int u = (t >= o) ? sh[t - o] : 0;
        __syncthreads();
        sh[t] += u;
        __syncthreads();
    }
    if (i < N) off[i] = sh[t] - v;
    if (t == 1023) bsum[blockIdx.x] = sh[t];
}

__global__ __launch_bounds__(128) void scan2_kernel(
    const int* __restrict__ bsum, int* __restrict__ boff, int nb)
{
    __shared__ int sh[128];
    int t = threadIdx.x;
    int v = (t < nb) ? bsum[t] : 0;
    sh[t] = v;
    __syncthreads();
#pragma unroll
    for (int o = 1; o < 128; o <<= 1) {
        int u = (t >= o) ? sh[t - o] : 0;
        __syncthreads();
        sh[t] += u;
        __syncthreads();
    }
    if (t < nb) boff[t] = sh[t] - v;
}

__global__ void scan3_kernel(int* __restrict__ off, const int* __restrict__ boff, int N) {
    int i = blockIdx.x * blockDim.x + threadIdx.x;
    if (i < N) off[i] += boff[i >> 10];
}

// ---------------------------------------------------------------------------
// P1: per-(block,bucket) histogram. LDS atomics only; sequential 4B writes.
// ---------------------------------------------------------------------------
__global__ __launch_bounds__(256) void count_kernel(
    const int* __restrict__ ei, int* __restrict__ counts, int E)
{
    __shared__ int cnt[256];
    for (int i = threadIdx.x; i < 256; i += 256) cnt[i] = 0;
    __syncthreads();
    const int e0 = blockIdx.x * EPB;
    const int e1 = min(e0 + EPB, E);
    for (int e = e0 + threadIdx.x; e < e1; e += 256)
        atomicAdd(&cnt[ei[E + e] >> 9], 1);
    __syncthreads();
    for (int b = threadIdx.x; b < 256; b += 256)
        counts[blockIdx.x * 256 + b] = cnt[b];
}

// ---------------------------------------------------------------------------
// P2: bases[blk][b] = off[b*BSZ] + prefix of counts over blocks. 1 block.
// ---------------------------------------------------------------------------
__global__ __launch_bounds__(256) void bases_kernel(
    const int* __restrict__ counts, const int* __restrict__ off,
    int* __restrict__ bases, int nblk, int N)
{
    int b = threadIdx.x;
    int base = ((long long)b * BSZ < N) ? off[b * BSZ] : 0;
    for (int blk = 0; blk < nblk; ++blk) {
        bases[blk * 256 + b] = base;
        base += counts[blk * 256 + b];
    }
}

// ---------------------------------------------------------------------------
// P3: place. Index phase assigns append slots from LDS counters (bases-
// initialized, deterministic totals), records pos/src. Copy phase streams
// fp32 ea sequentially and writes bf16 rows in ~2.7KB ascending bursts
// per bucket.
// ---------------------------------------------------------------------------
__global__ __launch_bounds__(256) void place_kernel(
    const float* __restrict__ ea, const int* __restrict__ ei,
    const int* __restrict__ off, int* __restrict__ cur,
    const int* __restrict__ bases, int* __restrict__ src_csr,
    int* __restrict__ pos, u16* __restrict__ stage, int E)
{
    __shared__ int cur2[256];
    __shared__ int qs[EPB];

    for (int i = threadIdx.x; i < 256; i += 256)
        cur2[i] = bases[blockIdx.x * 256 + i];
    __syncthreads();

    const int e0 = blockIdx.x * EPB;
    const int e1 = min(e0 + EPB, E);

    // ---- index phase ----
    for (int e = e0 + threadIdx.x; e < e1; e += 256) {
        int d = ei[E + e];
        int s = ei[e];
        int q = atomicAdd(&cur2[d >> 9], 1);          // LDS append slot
        int p = off[d] + atomicAdd(&cur[d], 1);       // CSR slot (per-node ctr)
        src_csr[p] = s;
        pos[p]     = q;
        qs[e - e0] = q;
    }
    __syncthreads();

    // ---- copy phase: 16 lanes/edge, 4 edges/wave-iter ----
    const int lane = threadIdx.x & 63;
    const int qd = lane & 15, g = lane >> 4;
    const int wid = threadIdx.x >> 6;
    const int cntE = e1 - e0;
    for (int i = wid * 4 + g; i < cntE; i += 16) {
        int e = e0 + i;
        int q = qs[i];
        float4 v = *(const float4*)&ea[(size_t)e * D + qd * 4];
        u64 pk = (u64)f2bf(v.x) | ((u64)f2bf(v.y) << 16)
               | ((u64)f2bf(v.z) << 32) | ((u64)f2bf(v.w) << 48);
        *(u64*)&stage[(size_t)q * D + qd * 4] = pk;
    }
}

// ---------------------------------------------------------------------------
// convx: fp32 node features -> bf16 (identity order, fully sequential)
// ---------------------------------------------------------------------------
__global__ __launch_bounds__(256) void convx_kernel(
    const float* __restrict__ xf, u16* __restrict__ xb, long long n4)
{
    long long i = (long long)blockIdx.x * blockDim.x + threadIdx.x;
    if (i >= n4) return;
    float4 v = ((const float4*)xf)[i];
    ushort4 o;
    o.x = f2bf(v.x); o.y = f2bf(v.y); o.z = f2bf(v.z); o.w = f2bf(v.w);
    ((ushort4*)xb)[i] = o;
}

// ---------------------------------------------------------------------------
// aggregate: wave per node, 8 lanes/edge, 8 edges per chunk, 2-deep pipeline.
// Edge rows at stage[pos[p]] (node's bucket window, L2-resident).
// h written in bf16 (MFMA A-operand format).
// ---------------------------------------------------------------------------
__global__ __launch_bounds__(256) void aggregate_kernel(
    const u16* __restrict__ xbf, const u16* __restrict__ stage,
    const int* __restrict__ src_csr, const int* __restrict__ pos,
    const int* __restrict__ off, const int* __restrict__ deg,
    u16* __restrict__ hbf, int N)
{
    const int lane = threadIdx.x & 63;
    const int sub  = lane & 7;        // dim octet
    const int g    = lane >> 3;       // edge slot 0..7
    const int n = (blockIdx.x << 2) + (threadIdx.x >> 6);
    if (n >= N) return;

    const int p0 = off[n];
    const int dg = deg[n];

    u16x8 xs;
    if (g == 0) xs = *(const u16x8*)&xbf[(size_t)n * D + sub * 8];

    float a0=0.f,a1=0.f,a2=0.f,a3=0.f,a4=0.f,a5=0.f,a6=0.f,a7=0.f;

    if (dg > 0) {
        const int pre    = p0 + min(lane, dg - 1);
        const int srcAll = src_csr[pre];
        const int posAll = pos[pre];
        const int nct = (dg + 7) >> 3;

        int e0 = min(g, dg - 1);
        int s0 = __shfl(srcAll, e0, 64);
        int q0 = __shfl(posAll, e0, 64);
        u16x8 evA = *(const u16x8*)&stage[(size_t)q0 * D + sub * 8];
        u16x8 xvA = *(const u16x8*)&xbf[(size_t)s0 * D + sub * 8];
        float mA = (g < dg) ? 1.f : 0.f;

        for (int c = 1; c < nct; ++c) {
            int e1 = min(c * 8 + g, dg - 1);
            int sv = __shfl(srcAll, e1 & 63, 64);
            int qv = __shfl(posAll, e1 & 63, 64);
            int s1 = (e1 < 64) ? sv : src_csr[p0 + e1];
            int q1 = (e1 < 64) ? qv : pos[p0 + e1];
            u16x8 evB = *(const u16x8*)&stage[(size_t)q1 * D + sub * 8];
            u16x8 xvB = *(const u16x8*)&xbf[(size_t)s1 * D + sub * 8];
            float mB = (c * 8 + g < dg) ? 1.f : 0.f;

            a0 = fmaf(mA, fmaxf(bf2f(xvA[0]) + bf2f(evA[0]), 0.f), a0);
            a1 = fmaf(mA, fmaxf(bf2f(xvA[1]) + bf2f(evA[1]), 0.f), a1);
            a2 = fmaf(mA, fmaxf(bf2f(xvA[2]) + bf2f(evA[2]), 0.f), a2);
            a3 = fmaf(mA, fmaxf(bf2f(xvA[3]) + bf2f(evA[3]), 0.f), a3);
            a4 = fmaf(mA, fmaxf(bf2f(xvA[4]) + bf2f(evA[4]), 0.f), a4);
            a5 = fmaf(mA, fmaxf(bf2f(xvA[5]) + bf2f(evA[5]), 0.f), a5);
            a6 = fmaf(mA, fmaxf(bf2f(xvA[6]) + bf2f(evA[6]), 0.f), a6);
            a7 = fmaf(mA, fmaxf(bf2f(xvA[7]) + bf2f(evA[7]), 0.f), a7);

            xvA = xvB; evA = evB; mA = mB;
        }
        a0 = fmaf(mA, fmaxf(bf2f(xvA[0]) + bf2f(evA[0]), 0.f), a0);
        a1 = fmaf(mA, fmaxf(bf2f(xvA[1]) + bf2f(evA[1]), 0.f), a1);
        a2 = fmaf(mA, fmaxf(bf2f(xvA[2]) + bf2f(evA[2]), 0.f), a2);
        a3 = fmaf(mA, fmaxf(bf2f(xvA[3]) + bf2f(evA[3]), 0.f), a3);
        a4 = fmaf(mA, fmaxf(bf2f(xvA[4]) + bf2f(evA[4]), 0.f), a4);
        a5 = fmaf(mA, fmaxf(bf2f(xvA[5]) + bf2f(evA[5]), 0.f), a5);
        a6 = fmaf(mA, fmaxf(bf2f(xvA[6]) + bf2f(evA[6]), 0.f), a6);
        a7 = fmaf(mA, fmaxf(bf2f(xvA[7]) + bf2f(evA[7]), 0.f), a7);
    }

#pragma unroll
    for (int o = 8; o < 64; o <<= 1) {
        a0 += __shfl_xor(a0, o, 64);  a1 += __shfl_xor(a1, o, 64);
        a2 += __shfl_xor(a2, o, 64);  a3 += __shfl_xor(a3, o, 64);
        a4 += __shfl_xor(a4, o, 64);  a5 += __shfl_xor(a5, o, 64);
        a6 += __shfl_xor(a6, o, 64);  a7 += __shfl_xor(a7, o, 64);
    }

    if (g == 0) {
        u16x8 ho;
        ho[0] = f2bf(a0 + bf2f(xs[0]));
        ho[1] = f2bf(a1 + bf2f(xs[1]));
        ho[2] = f2bf(a2 + bf2f(xs[2]));
        ho[3] = f2bf(a3 + bf2f(xs[3]));
        ho[4] = f2bf(a4 + bf2f(xs[4]));
        ho[5] = f2bf(a5 + bf2f(xs[5]));
        ho[6] = f2bf(a6 + bf2f(xs[6]));
        ho[7] = f2bf(a7 + bf2f(xs[7]));
        *(u16x8*)&hbf[(size_t)n * D + sub * 8] = ho;
    }
}

// ---------------------------------------------------------------------------
// MFMA MLP (as round 13): X = relu(relu(H@W1+b1)@W2+b2), bf16 in/out.
// ---------------------------------------------------------------------------
template <int LAST>
__global__ __launch_bounds__(256) void mlp_mfma_kernel(
    const u16* __restrict__ hbf, u16* __restrict__ xout,
    const float* __restrict__ W1, const float* __restrict__ b1,
    const float* __restrict__ W2, const float* __restrict__ b2,
    const int* __restrict__ batch, const float* __restrict__ Wout,
    float* __restrict__ out, int N, int ntiles)
{
    __shared__ __align__(16) u16 lds_h[4][16][72];
    __shared__ float pool[128];

    const int lane = threadIdx.x & 63;
    const int wid  = threadIdx.x >> 6;
    const int lr   = lane & 15;
    const int lg   = lane >> 4;

    if (LAST) {
        if (threadIdx.x < 128) pool[threadIdx.x] = 0.f;
        __syncthreads();
    }

    bf16x8 w1f[4][2], w2f[4][2];
#pragma unroll
    for (int nt = 0; nt < 4; ++nt)
#pragma unroll
      for (int ks = 0; ks < 2; ++ks) {
        bf16x8 f1, f2;
#pragma unroll
        for (int j = 0; j < 8; ++j) {
            int k = ks * 32 + lg * 8 + j;
            int c = nt * 16 + lr;
            f1[j] = (short)f2bf(W1[k * D + c]);
            f2[j] = (short)f2bf(W2[k * D + c]);
        }
        w1f[nt][ks] = f1; w2f[nt][ks] = f2;
      }
    float b1v[4], b2v[4], wov[4];
#pragma unroll
    for (int nt = 0; nt < 4; ++nt) {
        b1v[nt] = b1[nt * 16 + lr];
        b2v[nt] = b2[nt * 16 + lr];
        wov[nt] = LAST ? Wout[nt * 16 + lr] : 0.f;
    }

    for (int t = blockIdx.x; t < ntiles; t += gridDim.x) {
        const int m0 = t * 64 + wid * 16;
        if (m0 < N) {
            const int ra = min(m0 + lr, N - 1);
            bf16x8 a0 = *(const bf16x8*)&hbf[(size_t)ra * D + lg * 8];
            bf16x8 a1 = *(const bf16x8*)&hbf[(size_t)ra * D + 32 + lg * 8];

            f32x4 c1[4];
#pragma unroll
            for (int nt = 0; nt < 4; ++nt) {
                f32x4 z = {0.f, 0.f, 0.f, 0.f};
                z = __builtin_amdgcn_mfma_f32_16x16x32_bf16(a0, w1f[nt][0], z, 0, 0, 0);
                z = __builtin_amdgcn_mfma_f32_16x16x32_bf16(a1, w1f[nt][1], z, 0, 0, 0);
                c1[nt] = z;
            }
#pragma unroll
            for (int nt = 0; nt < 4; ++nt)
#pragma unroll
              for (int j = 0; j < 4; ++j) {
                float v = fmaxf(c1[nt][j] + b1v[nt], 0.f);
                lds_h[wid][lg * 4 + j][nt * 16 + lr] = f2bf(v);
              }

            bf16x8 h0 = *(const bf16x8*)&lds_h[wid][lr][lg * 8];
            bf16x8 h1 = *(const bf16x8*)&lds_h[wid][lr][32 + lg * 8];

            f32x4 c2[4];
#pragma unroll
            for (int nt = 0; nt < 4; ++nt) {
                f32x4 z = {0.f, 0.f, 0.f, 0.f};
                z = __builtin_amdgcn_mfma_f32_16x16x32_bf16(h0, w2f[nt][0], z, 0, 0, 0);
                z = __builtin_amdgcn_mfma_f32_16x16x32_bf16(h1, w2f[nt][1], z, 0, 0, 0);
                c2[nt] = z;
            }

            if (!LAST) {
#pragma unroll
                for (int nt = 0; nt < 4; ++nt)
#pragma unroll
                  for (int j = 0; j < 4; ++j) {
                    int gr = m0 + lg * 4 + j;
                    if (gr < N) {
                        float v = fmaxf(c2[nt][j] + b2v[nt], 0.f);
                        xout[(size_t)gr * D + nt * 16 + lr] = f2bf(v);
                    }
                  }
            } else {
                float s0 = 0.f, s1 = 0.f, s2 = 0.f, s3 = 0.f;
#pragma unroll
                for (int nt = 0; nt < 4; ++nt) {
                    s0 = fmaf(fmaxf(c2[nt][0] + b2v[nt], 0.f), wov[nt], s0);
                    s1 = fmaf(fmaxf(c2[nt][1] + b2v[nt], 0.f), wov[nt], s1);
                    s2 = fmaf(fmaxf(c2[nt][2] + b2v[nt], 0.f), wov[nt], s2);
                    s3 = fmaf(fmaxf(c2[nt][3] + b2v[nt], 0.f), wov[nt], s3);
                }
#pragma unroll
                for (int o = 1; o < 16; o <<= 1) {
                    s0 += __shfl_xor(s0, o, 64);
                    s1 += __shfl_xor(s1, o, 64);
                    s2 += __shfl_xor(s2, o, 64);
                    s3 += __shfl_xor(s3, o, 64);
                }
                if (lr == 0) {
                    int gr = m0 + lg * 4;
                    if (gr + 0 < N) atomicAdd(&pool[batch[gr + 0]], s0);
                    if (gr + 1 < N) atomicAdd(&pool[batch[gr + 1]], s1);
                    if (gr + 2 < N) atomicAdd(&pool[batch[gr + 2]], s2);
                    if (gr + 3 < N) atomicAdd(&pool[batch[gr + 3]], s3);
                }
            }
        }
    }

    if (LAST) {
        __syncthreads();
        if (threadIdx.x < 128) {
            float v = pool[threadIdx.x];
            if (v != 0.f) atomicAdd(&out[threadIdx.x], v);
        }
    }
}

// ---------------------------------------------------------------------------
extern "C" void kernel_launch(void* const* d_in, const int* in_sizes, int n_in,
                              void* d_out, int out_size, void* d_ws, size_t ws_size,
                              hipStream_t stream) {
    const float* x     = (const float*)d_in[0];
    const int*   ei    = (const int*)d_in[1];
    const float* ea    = (const float*)d_in[2];
    const int*   batch = (const int*)d_in[3];
    const float* W1    = (const float*)d_in[4];
    const float* b1    = (const float*)d_in[5];
    const float* W2    = (const float*)d_in[6];
    const float* b2    = (const float*)d_in[7];
    const float* Wout  = (const float*)d_in[8];
    const float* bout  = (const float*)d_in[9];
    float* out = (float*)d_out;

    const int N = in_sizes[0] / D;   // 100000
    const int E = in_sizes[1] / 2;   // 1200000
    const int G = out_size;          // 128
    const int nblk = (E + EPB - 1) / EPB;   // 293

    // ---- workspace layout ----
    char* w = (char*)d_ws;
    u16*   xbfA    = (u16*)w;              w += (size_t)N * D * sizeof(u16);
    u16*   xbfB    = (u16*)w;              w += (size_t)N * D * sizeof(u16);
    u16*   hbf     = (u16*)w;              w += (size_t)N * D * sizeof(u16);
    int*   src_csr = (int*)w;              w += (size_t)E * sizeof(int);
    int*   pos     = (int*)w;              w += (size_t)E * sizeof(int);
    int*   deg     = (int*)w;              w += (size_t)N * sizeof(int);
    int*   off     = (int*)w;              w += (size_t)N * sizeof(int);
    int*   cur     = (int*)w;              w += (size_t)N * sizeof(int);
    int*   counts  = (int*)w;              w += (size_t)nblk * 256 * sizeof(int);
    int*   bases   = (int*)w;              w += (size_t)nblk * 256 * sizeof(int);
    int*   bsum    = (int*)w;              w += 128 * sizeof(int);
    int*   boff    = (int*)w;              w += 128 * sizeof(int);
    u16*   stage   = (u16*)w;              // E*D*2 bytes

    const int nScanBlocks = (N + 1023) / 1024;
    const int edgeBlocks  = (E + 255) / 256;
    const int aggBlocks   = (N + 3) / 4;

    const long long nx4 = (long long)N * D / 4;
    const int convxBlocks = (int)((nx4 + 255) / 256);

    const int ntiles    = (N + 63) / 64;
    const int mlpBlocks = 782;

    out_init_kernel<<<(G + 127) / 128, 128, 0, stream>>>(out, bout, G);

    // ---- CSR build (deterministic bucketed partition) + x0 convert ----
    hipMemsetAsync(deg, 0, (size_t)N * sizeof(int), stream);
    hipMemsetAsync(cur, 0, (size_t)N * sizeof(int), stream);
    deg_hist_kernel<<<edgeBlocks, 256, 0, stream>>>(ei, deg, E);
    scan1_kernel<<<nScanBlocks, 1024, 0, stream>>>(deg, off, bsum, N);
    scan2_kernel<<<1, 128, 0, stream>>>(bsum, boff, nScanBlocks);
    scan3_kernel<<<(N + 255) / 256, 256, 0, stream>>>(off, boff, N);
    count_kernel<<<nblk, 256, 0, stream>>>(ei, counts, E);
    bases_kernel<<<1, 256, 0, stream>>>(counts, off, bases, nblk, N);
    place_kernel<<<nblk, 256, 0, stream>>>(ea, ei, off, cur, bases,
                                           src_csr, pos, stage, E);
    convx_kernel<<<convxBlocks, 256, 0, stream>>>(x, xbfA, nx4);

    // ---- 3 layers: aggregate -> MFMA mlp ----
    u16* xcur = xbfA;
    u16* xnxt = xbfB;
    for (int l = 0; l < 3; ++l) {
        aggregate_kernel<<<aggBlocks, 256, 0, stream>>>(xcur, stage, src_csr, pos,
                                                        off, deg, hbf, N);
        if (l < 2) {
            mlp_mfma_kernel<0><<<mlpBlocks, 256, 0, stream>>>(hbf, xnxt,
                W1 + l * D * D, b1 + l * D, W2 + l * D * D, b2 + l * D,
                batch, Wout, out, N, ntiles);
            u16* t = xcur; xcur = xnxt; xnxt = t;
        } else {
            mlp_mfma_kernel<1><<<mlpBlocks, 256, 0, stream>>>(hbf, nullptr,
                W1 + l * D * D, b1 + l * D, W2 + l * D * D, b2 + l * D,
                batch, Wout, out, N, ntiles);
        }
    }
}

// Round 15
// 376.711 us; speedup vs baseline: 1.6235x; 1.6235x over previous
//
#include <hip/hip_runtime.h>
#include <hip/hip_bf16.h>

#define D 64

typedef unsigned short u16;
typedef unsigned long long u64;
typedef __attribute__((ext_vector_type(8))) unsigned short u16x8;
typedef __attribute__((ext_vector_type(8))) short bf16x8;
typedef __attribute__((ext_vector_type(4))) float f32x4;

static __device__ __forceinline__ u16 f2bf(float f) {
    unsigned u = __float_as_uint(f);
    unsigned r = (u + 0x7FFFu + ((u >> 16) & 1u)) >> 16;   // RNE
    return (u16)r;
}
static __device__ __forceinline__ float bf2f(u16 h) {
    return __uint_as_float(((unsigned)h) << 16);
}

// ---------------------------------------------------------------------------
// init: out[g]=bout, deg=0, cur=0  (replaces 2 memsets + out_init)
// ---------------------------------------------------------------------------
__global__ void init_kernel(float* __restrict__ out, const float* __restrict__ bout,
                            int* __restrict__ deg, int* __restrict__ cur, int N, int G) {
    int i = blockIdx.x * blockDim.x + threadIdx.x;
    if (i < N) { deg[i] = 0; cur[i] = 0; }
    if (i < G) out[i] = bout[0];
}

// ---------------------------------------------------------------------------
// CSR build: histogram -> scan (boff applied on the fly by consumers)
// ---------------------------------------------------------------------------
__global__ void deg_hist_kernel(const int* __restrict__ ei, int* __restrict__ deg, int E) {
    int e = blockIdx.x * blockDim.x + threadIdx.x;
    if (e < E) atomicAdd(&deg[ei[E + e]], 1);
}

__global__ __launch_bounds__(1024) void scan1_kernel(
    const int* __restrict__ deg, int* __restrict__ off, int* __restrict__ bsum, int N)
{
    __shared__ int sh[1024];
    int t = threadIdx.x;
    int i = blockIdx.x * 1024 + t;
    int v = (i < N) ? deg[i] : 0;
    sh[t] = v;
    __syncthreads();
#pragma unroll
    for (int o = 1; o < 1024; o <<= 1) {
        int u = (t >= o) ? sh[t - o] : 0;
        __syncthreads();
        sh[t] += u;
        __syncthreads();
    }
    if (i < N) off[i] = sh[t] - v;
    if (t == 1023) bsum[blockIdx.x] = sh[t];
}

__global__ __launch_bounds__(128) void scan2_kernel(
    const int* __restrict__ bsum, int* __restrict__ boff, int nb)
{
    __shared__ int sh[128];
    int t = threadIdx.x;
    int v = (t < nb) ? bsum[t] : 0;
    sh[t] = v;
    __syncthreads();
#pragma unroll
    for (int o = 1; o < 128; o <<= 1) {
        int u = (t >= o) ? sh[t - o] : 0;
        __syncthreads();
        sh[t] += u;
        __syncthreads();
    }
    if (t < nb) boff[t] = sh[t] - v;
}

// ---------------------------------------------------------------------------
// build: fused scatter + reorder.  Wave handles 4 edges, 16 lanes/edge.
// Sequential fp32 ea read, bf16 row (128B) NT write to exact CSR slot.
// p = off[d] + boff[d>>10] + cur[d]++  (scan3 folded in)
// ---------------------------------------------------------------------------
__global__ __launch_bounds__(256) void build_kernel(
    const float* __restrict__ ea, const int* __restrict__ ei,
    const int* __restrict__ off, const int* __restrict__ boff, int* __restrict__ cur,
    int* __restrict__ src_csr, u16* __restrict__ ea_csr, int E)
{
    const int lane = threadIdx.x & 63;
    const int q = lane & 15, g = lane >> 4;
    const long long wv = (long long)blockIdx.x * 4 + (threadIdx.x >> 6);
    const int e = (int)(wv * 4) + g;

    int p = 0, s = 0;
    if (e < E && q == 0) {
        int d = ei[E + e];
        s = ei[e];
        p = off[d] + boff[d >> 10] + atomicAdd(&cur[d], 1);
    }
    p = __shfl(p, lane & 48, 64);        // broadcast group leader's slot
    if (e >= E) return;

    float4 v = *(const float4*)&ea[(size_t)e * D + q * 4];
    u64 pk = (u64)f2bf(v.x) | ((u64)f2bf(v.y) << 16)
           | ((u64)f2bf(v.z) << 32) | ((u64)f2bf(v.w) << 48);
    __builtin_nontemporal_store(pk, (u64*)&ea_csr[(size_t)p * D + q * 4]);
    if (q == 0) src_csr[p] = s;
}

// ---------------------------------------------------------------------------
// convx: fp32 node features -> bf16 (identity order, fully sequential)
// ---------------------------------------------------------------------------
__global__ __launch_bounds__(256) void convx_kernel(
    const float* __restrict__ xf, u16* __restrict__ xb, long long n4)
{
    long long i = (long long)blockIdx.x * blockDim.x + threadIdx.x;
    if (i >= n4) return;
    float4 v = ((const float4*)xf)[i];
    ushort4 o;
    o.x = f2bf(v.x); o.y = f2bf(v.y); o.z = f2bf(v.z); o.w = f2bf(v.w);
    ((ushort4*)xb)[i] = o;
}

// ---------------------------------------------------------------------------
// aggregate: wave per node, 8 lanes/edge, 8 edges per chunk, 2-deep pipeline.
// Sequential bf16 ea_csr stream (exact CSR placement -> a node's rows are
// contiguous); h written in bf16 (MFMA A-operand format).
// ---------------------------------------------------------------------------
__global__ __launch_bounds__(256) void aggregate_kernel(
    const u16* __restrict__ xbf, const u16* __restrict__ ea_csr,
    const int* __restrict__ src_csr, const int* __restrict__ off,
    const int* __restrict__ boff, const int* __restrict__ deg,
    u16* __restrict__ hbf, int N)
{
    const int lane = threadIdx.x & 63;
    const int sub  = lane & 7;        // dim octet
    const int g    = lane >> 3;       // edge slot 0..7
    const int n = (blockIdx.x << 2) + (threadIdx.x >> 6);
    if (n >= N) return;

    const int p0 = off[n] + boff[n >> 10];
    const int dg = deg[n];

    u16x8 xs;                          // self row (consumed at the end)
    if (g == 0) xs = *(const u16x8*)&xbf[(size_t)n * D + sub * 8];

    float a0=0.f,a1=0.f,a2=0.f,a3=0.f,a4=0.f,a5=0.f,a6=0.f,a7=0.f;

    if (dg > 0) {
        const int srcAll = src_csr[p0 + min(lane, dg - 1)];  // one coalesced load
        const int nct = (dg + 7) >> 3;

        // ---- issue chunk 0 ----
        int e0 = min(g, dg - 1);
        int s0 = __shfl(srcAll, e0, 64);
        u16x8 evA = *(const u16x8*)&ea_csr[(size_t)(p0 + e0) * D + sub * 8];
        u16x8 xvA = *(const u16x8*)&xbf[(size_t)s0 * D + sub * 8];
        float mA = (g < dg) ? 1.f : 0.f;

        for (int c = 1; c < nct; ++c) {
            int e1 = min(c * 8 + g, dg - 1);
            int sv1 = __shfl(srcAll, e1 & 63, 64);
            int s1 = (e1 < 64) ? sv1 : src_csr[p0 + e1];
            u16x8 evB = *(const u16x8*)&ea_csr[(size_t)(p0 + e1) * D + sub * 8];
            u16x8 xvB = *(const u16x8*)&xbf[(size_t)s1 * D + sub * 8];
            float mB = (c * 8 + g < dg) ? 1.f : 0.f;

            a0 = fmaf(mA, fmaxf(bf2f(xvA[0]) + bf2f(evA[0]), 0.f), a0);
            a1 = fmaf(mA, fmaxf(bf2f(xvA[1]) + bf2f(evA[1]), 0.f), a1);
            a2 = fmaf(mA, fmaxf(bf2f(xvA[2]) + bf2f(evA[2]), 0.f), a2);
            a3 = fmaf(mA, fmaxf(bf2f(xvA[3]) + bf2f(evA[3]), 0.f), a3);
            a4 = fmaf(mA, fmaxf(bf2f(xvA[4]) + bf2f(evA[4]), 0.f), a4);
            a5 = fmaf(mA, fmaxf(bf2f(xvA[5]) + bf2f(evA[5]), 0.f), a5);
            a6 = fmaf(mA, fmaxf(bf2f(xvA[6]) + bf2f(evA[6]), 0.f), a6);
            a7 = fmaf(mA, fmaxf(bf2f(xvA[7]) + bf2f(evA[7]), 0.f), a7);

            xvA = xvB; evA = evB; mA = mB;
        }
        a0 = fmaf(mA, fmaxf(bf2f(xvA[0]) + bf2f(evA[0]), 0.f), a0);
        a1 = fmaf(mA, fmaxf(bf2f(xvA[1]) + bf2f(evA[1]), 0.f), a1);
        a2 = fmaf(mA, fmaxf(bf2f(xvA[2]) + bf2f(evA[2]), 0.f), a2);
        a3 = fmaf(mA, fmaxf(bf2f(xvA[3]) + bf2f(evA[3]), 0.f), a3);
        a4 = fmaf(mA, fmaxf(bf2f(xvA[4]) + bf2f(evA[4]), 0.f), a4);
        a5 = fmaf(mA, fmaxf(bf2f(xvA[5]) + bf2f(evA[5]), 0.f), a5);
        a6 = fmaf(mA, fmaxf(bf2f(xvA[6]) + bf2f(evA[6]), 0.f), a6);
        a7 = fmaf(mA, fmaxf(bf2f(xvA[7]) + bf2f(evA[7]), 0.f), a7);
    }

    // reduce across the 8 edge-groups
#pragma unroll
    for (int o = 8; o < 64; o <<= 1) {
        a0 += __shfl_xor(a0, o, 64);  a1 += __shfl_xor(a1, o, 64);
        a2 += __shfl_xor(a2, o, 64);  a3 += __shfl_xor(a3, o, 64);
        a4 += __shfl_xor(a4, o, 64);  a5 += __shfl_xor(a5, o, 64);
        a6 += __shfl_xor(a6, o, 64);  a7 += __shfl_xor(a7, o, 64);
    }

    if (g == 0) {
        u16x8 ho;
        ho[0] = f2bf(a0 + bf2f(xs[0]));
        ho[1] = f2bf(a1 + bf2f(xs[1]));
        ho[2] = f2bf(a2 + bf2f(xs[2]));
        ho[3] = f2bf(a3 + bf2f(xs[3]));
        ho[4] = f2bf(a4 + bf2f(xs[4]));
        ho[5] = f2bf(a5 + bf2f(xs[5]));
        ho[6] = f2bf(a6 + bf2f(xs[6]));
        ho[7] = f2bf(a7 + bf2f(xs[7]));
        *(u16x8*)&hbf[(size_t)n * D + sub * 8] = ho;
    }
}

// ---------------------------------------------------------------------------
// MFMA MLP: X = relu(relu(H@W1+b1)@W2+b2), H bf16 row-major.
// Block = 4 waves; M-tile 64 rows (16/wave). W1,W2 held as B-fragments in
// VGPRs (loaded once per block, amortized via grid-stride). Hidden
// redistributed through padded LDS (stride 72 -> 2-way conflicts only).
// LAST=1: fused global_add_pool via LDS 128-bin accumulation + Wout.
// ---------------------------------------------------------------------------
template <int LAST>
__global__ __launch_bounds__(256) void mlp_mfma_kernel(
    const u16* __restrict__ hbf, u16* __restrict__ xout,
    const float* __restrict__ W1, const float* __restrict__ b1,
    const float* __restrict__ W2, const float* __restrict__ b2,
    const int* __restrict__ batch, const float* __restrict__ Wout,
    float* __restrict__ out, int N, int ntiles)
{
    __shared__ __align__(16) u16 lds_h[4][16][72];
    __shared__ float pool[128];

    const int lane = threadIdx.x & 63;
    const int wid  = threadIdx.x >> 6;
    const int lr   = lane & 15;
    const int lg   = lane >> 4;

    if (LAST) {
        if (threadIdx.x < 128) pool[threadIdx.x] = 0.f;
        __syncthreads();
    }

    bf16x8 w1f[4][2], w2f[4][2];
#pragma unroll
    for (int nt = 0; nt < 4; ++nt)
#pragma unroll
      for (int ks = 0; ks < 2; ++ks) {
        bf16x8 f1, f2;
#pragma unroll
        for (int j = 0; j < 8; ++j) {
            int k = ks * 32 + lg * 8 + j;
            int c = nt * 16 + lr;
            f1[j] = (short)f2bf(W1[k * D + c]);
            f2[j] = (short)f2bf(W2[k * D + c]);
        }
        w1f[nt][ks] = f1; w2f[nt][ks] = f2;
      }
    float b1v[4], b2v[4], wov[4];
#pragma unroll
    for (int nt = 0; nt < 4; ++nt) {
        b1v[nt] = b1[nt * 16 + lr];
        b2v[nt] = b2[nt * 16 + lr];
        wov[nt] = LAST ? Wout[nt * 16 + lr] : 0.f;
    }

    for (int t = blockIdx.x; t < ntiles; t += gridDim.x) {
        const int m0 = t * 64 + wid * 16;
        if (m0 < N) {
            const int ra = min(m0 + lr, N - 1);
            bf16x8 a0 = *(const bf16x8*)&hbf[(size_t)ra * D + lg * 8];
            bf16x8 a1 = *(const bf16x8*)&hbf[(size_t)ra * D + 32 + lg * 8];

            f32x4 c1[4];
#pragma unroll
            for (int nt = 0; nt < 4; ++nt) {
                f32x4 z = {0.f, 0.f, 0.f, 0.f};
                z = __builtin_amdgcn_mfma_f32_16x16x32_bf16(a0, w1f[nt][0], z, 0, 0, 0);
                z = __builtin_amdgcn_mfma_f32_16x16x32_bf16(a1, w1f[nt][1], z, 0, 0, 0);
                c1[nt] = z;
            }
#pragma unroll
            for (int nt = 0; nt < 4; ++nt)
#pragma unroll
              for (int j = 0; j < 4; ++j) {
                float v = fmaxf(c1[nt][j] + b1v[nt], 0.f);
                lds_h[wid][lg * 4 + j][nt * 16 + lr] = f2bf(v);
              }

            bf16x8 h0 = *(const bf16x8*)&lds_h[wid][lr][lg * 8];
            bf16x8 h1 = *(const bf16x8*)&lds_h[wid][lr][32 + lg * 8];

            f32x4 c2[4];
#pragma unroll
            for (int nt = 0; nt < 4; ++nt) {
                f32x4 z = {0.f, 0.f, 0.f, 0.f};
                z = __builtin_amdgcn_mfma_f32_16x16x32_bf16(h0, w2f[nt][0], z, 0, 0, 0);
                z = __builtin_amdgcn_mfma_f32_16x16x32_bf16(h1, w2f[nt][1], z, 0, 0, 0);
                c2[nt] = z;
            }

            if (!LAST) {
#pragma unroll
                for (int nt = 0; nt < 4; ++nt)
#pragma unroll
                  for (int j = 0; j < 4; ++j) {
                    int gr = m0 + lg * 4 + j;
                    if (gr < N) {
                        float v = fmaxf(c2[nt][j] + b2v[nt], 0.f);
                        xout[(size_t)gr * D + nt * 16 + lr] = f2bf(v);
                    }
                  }
            } else {
                float s0 = 0.f, s1 = 0.f, s2 = 0.f, s3 = 0.f;
#pragma unroll
                for (int nt = 0; nt < 4; ++nt) {
                    s0 = fmaf(fmaxf(c2[nt][0] + b2v[nt], 0.f), wov[nt], s0);
                    s1 = fmaf(fmaxf(c2[nt][1] + b2v[nt], 0.f), wov[nt], s1);
                    s2 = fmaf(fmaxf(c2[nt][2] + b2v[nt], 0.f), wov[nt], s2);
                    s3 = fmaf(fmaxf(c2[nt][3] + b2v[nt], 0.f), wov[nt], s3);
                }
#pragma unroll
                for (int o = 1; o < 16; o <<= 1) {
                    s0 += __shfl_xor(s0, o, 64);
                    s1 += __shfl_xor(s1, o, 64);
                    s2 += __shfl_xor(s2, o, 64);
                    s3 += __shfl_xor(s3, o, 64);
                }
                if (lr == 0) {
                    int gr = m0 + lg * 4;
                    if (gr + 0 < N) atomicAdd(&pool[batch[gr + 0]], s0);
                    if (gr + 1 < N) atomicAdd(&pool[batch[gr + 1]], s1);
                    if (gr + 2 < N) atomicAdd(&pool[batch[gr + 2]], s2);
                    if (gr + 3 < N) atomicAdd(&pool[batch[gr + 3]], s3);
                }
            }
        }
    }

    if (LAST) {
        __syncthreads();
        if (threadIdx.x < 128) {
            float v = pool[threadIdx.x];
            if (v != 0.f) atomicAdd(&out[threadIdx.x], v);
        }
    }
}

// ---------------------------------------------------------------------------
extern "C" void kernel_launch(void* const* d_in, const int* in_sizes, int n_in,
                              void* d_out, int out_size, void* d_ws, size_t ws_size,
                              hipStream_t stream) {
    const float* x     = (const float*)d_in[0];
    const int*   ei    = (const int*)d_in[1];
    const float* ea    = (const float*)d_in[2];
    const int*   batch = (const int*)d_in[3];
    const float* W1    = (const float*)d_in[4];
    const float* b1    = (const float*)d_in[5];
    const float* W2    = (const float*)d_in[6];
    const float* b2    = (const float*)d_in[7];
    const float* Wout  = (const float*)d_in[8];
    const float* bout  = (const float*)d_in[9];
    float* out = (float*)d_out;

    const int N = in_sizes[0] / D;   // 100000
    const int E = in_sizes[1] / 2;   // 1200000
    const int G = out_size;          // 128

    // ---- workspace layout ----
    char* w = (char*)d_ws;
    u16*   xbfA    = (u16*)w;              w += (size_t)N * D * sizeof(u16);
    u16*   xbfB    = (u16*)w;              w += (size_t)N * D * sizeof(u16);
    u16*   hbf     = (u16*)w;              w += (size_t)N * D * sizeof(u16);
    int*   src_csr = (int*)w;              w += (size_t)E * sizeof(int);
    int*   deg     = (int*)w;              w += (size_t)N * sizeof(int);
    int*   off     = (int*)w;              w += (size_t)N * sizeof(int);
    int*   cur     = (int*)w;              w += (size_t)N * sizeof(int);
    int*   bsum    = (int*)w;              w += 128 * sizeof(int);
    int*   boff    = (int*)w;              w += 128 * sizeof(int);
    u16*   ea_csr  = (u16*)w;              // E*D*2 bytes

    const int nScanBlocks = (N + 1023) / 1024;
    const int edgeBlocks  = (E + 255) / 256;
    const int buildBlocks = (E + 15) / 16;
    const int aggBlocks   = (N + 3) / 4;       // one wave per node

    const long long nx4 = (long long)N * D / 4;
    const int convxBlocks = (int)((nx4 + 255) / 256);

    const int ntiles    = (N + 63) / 64;       // 1563
    const int mlpBlocks = 782;

    // ---- init (out=bout, deg=0, cur=0) ----
    init_kernel<<<(N + 255) / 256, 256, 0, stream>>>(out, bout, deg, cur, N, G);

    // ---- CSR build + bf16 edge reorder + x0 bf16 convert ----
    deg_hist_kernel<<<edgeBlocks, 256, 0, stream>>>(ei, deg, E);
    scan1_kernel<<<nScanBlocks, 1024, 0, stream>>>(deg, off, bsum, N);
    scan2_kernel<<<1, 128, 0, stream>>>(bsum, boff, nScanBlocks);
    build_kernel<<<buildBlocks, 256, 0, stream>>>(ea, ei, off, boff, cur,
                                                  src_csr, ea_csr, E);
    convx_kernel<<<convxBlocks, 256, 0, stream>>>(x, xbfA, nx4);

    // ---- 3 layers: aggregate -> MFMA mlp ----
    u16* xcur = xbfA;
    u16* xnxt = xbfB;
    for (int l = 0; l < 3; ++l) {
        aggregate_kernel<<<aggBlocks, 256, 0, stream>>>(xcur, ea_csr, src_csr,
                                                        off, boff, deg, hbf, N);
        if (l < 2) {
            mlp_mfma_kernel<0><<<mlpBlocks, 256, 0, stream>>>(hbf, xnxt,
                W1 + l * D * D, b1 + l * D, W2 + l * D * D, b2 + l * D,
                batch, Wout, out, N, ntiles);
            u16* t = xcur; xcur = xnxt; xnxt = t;
        } else {
            mlp_mfma_kernel<1><<<mlpBlocks, 256, 0, stream>>>(hbf, nullptr,
                W1 + l * D * D, b1 + l * D, W2 + l * D * D, b2 + l * D,
                batch, Wout, out, N, ntiles);
        }
    }
}

// Round 16
// 372.732 us; speedup vs baseline: 1.6408x; 1.0107x over previous
//
#include <hip/hip_runtime.h>
#include <hip/hip_bf16.h>

#define D 64

typedef unsigned short u16;
typedef unsigned long long u64;
typedef __attribute__((ext_vector_type(8))) unsigned short u16x8;
typedef __attribute__((ext_vector_type(8))) short bf16x8;
typedef __attribute__((ext_vector_type(4))) float f32x4;

static __device__ __forceinline__ u16 f2bf(float f) {
    unsigned u = __float_as_uint(f);
    unsigned r = (u + 0x7FFFu + ((u >> 16) & 1u)) >> 16;   // RNE
    return (u16)r;
}
static __device__ __forceinline__ float bf2f(u16 h) {
    return __uint_as_float(((unsigned)h) << 16);
}

// ---------------------------------------------------------------------------
// init: out[g]=bout, deg=0, cur=0
// ---------------------------------------------------------------------------
__global__ void init_kernel(float* __restrict__ out, const float* __restrict__ bout,
                            int* __restrict__ deg, int* __restrict__ cur, int N, int G) {
    int i = blockIdx.x * blockDim.x + threadIdx.x;
    if (i < N) { deg[i] = 0; cur[i] = 0; }
    if (i < G) out[i] = bout[0];
}

// ---------------------------------------------------------------------------
// CSR build: histogram -> scan (boff applied on the fly by consumers)
// ---------------------------------------------------------------------------
__global__ void deg_hist_kernel(const int* __restrict__ ei, int* __restrict__ deg, int E) {
    int e = blockIdx.x * blockDim.x + threadIdx.x;
    if (e < E) atomicAdd(&deg[ei[E + e]], 1);
}

__global__ __launch_bounds__(1024) void scan1_kernel(
    const int* __restrict__ deg, int* __restrict__ off, int* __restrict__ bsum, int N)
{
    __shared__ int sh[1024];
    int t = threadIdx.x;
    int i = blockIdx.x * 1024 + t;
    int v = (i < N) ? deg[i] : 0;
    sh[t] = v;
    __syncthreads();
#pragma unroll
    for (int o = 1; o < 1024; o <<= 1) {
        int u = (t >= o) ? sh[t - o] : 0;
        __syncthreads();
        sh[t] += u;
        __syncthreads();
    }
    if (i < N) off[i] = sh[t] - v;
    if (t == 1023) bsum[blockIdx.x] = sh[t];
}

__global__ __launch_bounds__(128) void scan2_kernel(
    const int* __restrict__ bsum, int* __restrict__ boff, int nb)
{
    __shared__ int sh[128];
    int t = threadIdx.x;
    int v = (t < nb) ? bsum[t] : 0;
    sh[t] = v;
    __syncthreads();
#pragma unroll
    for (int o = 1; o < 128; o <<= 1) {
        int u = (t >= o) ? sh[t - o] : 0;
        __syncthreads();
        sh[t] += u;
        __syncthreads();
    }
    if (t < nb) boff[t] = sh[t] - v;
}

// ---------------------------------------------------------------------------
// build: fused scatter + reorder.  Wave handles 4 edges, 16 lanes/edge.
// Sequential fp32 ea read, bf16 row (128B) CACHED write to exact CSR slot
// (no NT: stage stream stays L3-resident for the 3 agg passes).
// ---------------------------------------------------------------------------
__global__ __launch_bounds__(256) void build_kernel(
    const float* __restrict__ ea, const int* __restrict__ ei,
    const int* __restrict__ off, const int* __restrict__ boff, int* __restrict__ cur,
    int* __restrict__ src_csr, u16* __restrict__ ea_csr, int E)
{
    const int lane = threadIdx.x & 63;
    const int q = lane & 15, g = lane >> 4;
    const long long wv = (long long)blockIdx.x * 4 + (threadIdx.x >> 6);
    const int e = (int)(wv * 4) + g;

    int p = 0, s = 0;
    if (e < E && q == 0) {
        int d = ei[E + e];
        s = ei[e];
        p = off[d] + boff[d >> 10] + atomicAdd(&cur[d], 1);
    }
    p = __shfl(p, lane & 48, 64);        // broadcast group leader's slot
    if (e >= E) return;

    float4 v = *(const float4*)&ea[(size_t)e * D + q * 4];
    u64 pk = (u64)f2bf(v.x) | ((u64)f2bf(v.y) << 16)
           | ((u64)f2bf(v.z) << 32) | ((u64)f2bf(v.w) << 48);
    *(u64*)&ea_csr[(size_t)p * D + q * 4] = pk;
    if (q == 0) src_csr[p] = s;
}

// ---------------------------------------------------------------------------
// convx: fp32 node features -> bf16 (identity order, fully sequential)
// ---------------------------------------------------------------------------
__global__ __launch_bounds__(256) void convx_kernel(
    const float* __restrict__ xf, u16* __restrict__ xb, long long n4)
{
    long long i = (long long)blockIdx.x * blockDim.x + threadIdx.x;
    if (i >= n4) return;
    float4 v = ((const float4*)xf)[i];
    ushort4 o;
    o.x = f2bf(v.x); o.y = f2bf(v.y); o.z = f2bf(v.z); o.w = f2bf(v.w);
    ((ushort4*)xb)[i] = o;
}

// ---------------------------------------------------------------------------
// aggregate: wave per node, 8 lanes/edge, 8 edges per chunk, 2-deep pipeline.
// Sequential bf16 ea_csr stream (L3-resident); h written in bf16.
// ---------------------------------------------------------------------------
__global__ __launch_bounds__(256) void aggregate_kernel(
    const u16* __restrict__ xbf, const u16* __restrict__ ea_csr,
    const int* __restrict__ src_csr, const int* __restrict__ off,
    const int* __restrict__ boff, const int* __restrict__ deg,
    u16* __restrict__ hbf, int N)
{
    const int lane = threadIdx.x & 63;
    const int sub  = lane & 7;        // dim octet
    const int g    = lane >> 3;       // edge slot 0..7
    const int n = (blockIdx.x << 2) + (threadIdx.x >> 6);
    if (n >= N) return;

    const int p0 = off[n] + boff[n >> 10];
    const int dg = deg[n];

    u16x8 xs;                          // self row (consumed at the end)
    if (g == 0) xs = *(const u16x8*)&xbf[(size_t)n * D + sub * 8];

    float a0=0.f,a1=0.f,a2=0.f,a3=0.f,a4=0.f,a5=0.f,a6=0.f,a7=0.f;

    if (dg > 0) {
        const int srcAll = src_csr[p0 + min(lane, dg - 1)];  // one coalesced load
        const int nct = (dg + 7) >> 3;

        // ---- issue chunk 0 ----
        int e0 = min(g, dg - 1);
        int s0 = __shfl(srcAll, e0, 64);
        u16x8 evA = *(const u16x8*)&ea_csr[(size_t)(p0 + e0) * D + sub * 8];
        u16x8 xvA = *(const u16x8*)&xbf[(size_t)s0 * D + sub * 8];
        float mA = (g < dg) ? 1.f : 0.f;

        for (int c = 1; c < nct; ++c) {
            int e1 = min(c * 8 + g, dg - 1);
            int sv1 = __shfl(srcAll, e1 & 63, 64);
            int s1 = (e1 < 64) ? sv1 : src_csr[p0 + e1];
            u16x8 evB = *(const u16x8*)&ea_csr[(size_t)(p0 + e1) * D + sub * 8];
            u16x8 xvB = *(const u16x8*)&xbf[(size_t)s1 * D + sub * 8];
            float mB = (c * 8 + g < dg) ? 1.f : 0.f;

            a0 = fmaf(mA, fmaxf(bf2f(xvA[0]) + bf2f(evA[0]), 0.f), a0);
            a1 = fmaf(mA, fmaxf(bf2f(xvA[1]) + bf2f(evA[1]), 0.f), a1);
            a2 = fmaf(mA, fmaxf(bf2f(xvA[2]) + bf2f(evA[2]), 0.f), a2);
            a3 = fmaf(mA, fmaxf(bf2f(xvA[3]) + bf2f(evA[3]), 0.f), a3);
            a4 = fmaf(mA, fmaxf(bf2f(xvA[4]) + bf2f(evA[4]), 0.f), a4);
            a5 = fmaf(mA, fmaxf(bf2f(xvA[5]) + bf2f(evA[5]), 0.f), a5);
            a6 = fmaf(mA, fmaxf(bf2f(xvA[6]) + bf2f(evA[6]), 0.f), a6);
            a7 = fmaf(mA, fmaxf(bf2f(xvA[7]) + bf2f(evA[7]), 0.f), a7);

            xvA = xvB; evA = evB; mA = mB;
        }
        a0 = fmaf(mA, fmaxf(bf2f(xvA[0]) + bf2f(evA[0]), 0.f), a0);
        a1 = fmaf(mA, fmaxf(bf2f(xvA[1]) + bf2f(evA[1]), 0.f), a1);
        a2 = fmaf(mA, fmaxf(bf2f(xvA[2]) + bf2f(evA[2]), 0.f), a2);
        a3 = fmaf(mA, fmaxf(bf2f(xvA[3]) + bf2f(evA[3]), 0.f), a3);
        a4 = fmaf(mA, fmaxf(bf2f(xvA[4]) + bf2f(evA[4]), 0.f), a4);
        a5 = fmaf(mA, fmaxf(bf2f(xvA[5]) + bf2f(evA[5]), 0.f), a5);
        a6 = fmaf(mA, fmaxf(bf2f(xvA[6]) + bf2f(evA[6]), 0.f), a6);
        a7 = fmaf(mA, fmaxf(bf2f(xvA[7]) + bf2f(evA[7]), 0.f), a7);
    }

    // reduce across the 8 edge-groups
#pragma unroll
    for (int o = 8; o < 64; o <<= 1) {
        a0 += __shfl_xor(a0, o, 64);  a1 += __shfl_xor(a1, o, 64);
        a2 += __shfl_xor(a2, o, 64);  a3 += __shfl_xor(a3, o, 64);
        a4 += __shfl_xor(a4, o, 64);  a5 += __shfl_xor(a5, o, 64);
        a6 += __shfl_xor(a6, o, 64);  a7 += __shfl_xor(a7, o, 64);
    }

    if (g == 0) {
        u16x8 ho;
        ho[0] = f2bf(a0 + bf2f(xs[0]));
        ho[1] = f2bf(a1 + bf2f(xs[1]));
        ho[2] = f2bf(a2 + bf2f(xs[2]));
        ho[3] = f2bf(a3 + bf2f(xs[3]));
        ho[4] = f2bf(a4 + bf2f(xs[4]));
        ho[5] = f2bf(a5 + bf2f(xs[5]));
        ho[6] = f2bf(a6 + bf2f(xs[6]));
        ho[7] = f2bf(a7 + bf2f(xs[7]));
        *(u16x8*)&hbf[(size_t)n * D + sub * 8] = ho;
    }
}

// ---------------------------------------------------------------------------
// MFMA MLP: X = relu(relu(H@W1+b1)@W2+b2), H bf16 row-major.
// ---------------------------------------------------------------------------
template <int LAST>
__global__ __launch_bounds__(256) void mlp_mfma_kernel(
    const u16* __restrict__ hbf, u16* __restrict__ xout,
    const float* __restrict__ W1, const float* __restrict__ b1,
    const float* __restrict__ W2, const float* __restrict__ b2,
    const int* __restrict__ batch, const float* __restrict__ Wout,
    float* __restrict__ out, int N, int ntiles)
{
    __shared__ __align__(16) u16 lds_h[4][16][72];
    __shared__ float pool[128];

    const int lane = threadIdx.x & 63;
    const int wid  = threadIdx.x >> 6;
    const int lr   = lane & 15;
    const int lg   = lane >> 4;

    if (LAST) {
        if (threadIdx.x < 128) pool[threadIdx.x] = 0.f;
        __syncthreads();
    }

    bf16x8 w1f[4][2], w2f[4][2];
#pragma unroll
    for (int nt = 0; nt < 4; ++nt)
#pragma unroll
      for (int ks = 0; ks < 2; ++ks) {
        bf16x8 f1, f2;
#pragma unroll
        for (int j = 0; j < 8; ++j) {
            int k = ks * 32 + lg * 8 + j;
            int c = nt * 16 + lr;
            f1[j] = (short)f2bf(W1[k * D + c]);
            f2[j] = (short)f2bf(W2[k * D + c]);
        }
        w1f[nt][ks] = f1; w2f[nt][ks] = f2;
      }
    float b1v[4], b2v[4], wov[4];
#pragma unroll
    for (int nt = 0; nt < 4; ++nt) {
        b1v[nt] = b1[nt * 16 + lr];
        b2v[nt] = b2[nt * 16 + lr];
        wov[nt] = LAST ? Wout[nt * 16 + lr] : 0.f;
    }

    for (int t = blockIdx.x; t < ntiles; t += gridDim.x) {
        const int m0 = t * 64 + wid * 16;
        if (m0 < N) {
            const int ra = min(m0 + lr, N - 1);
            bf16x8 a0 = *(const bf16x8*)&hbf[(size_t)ra * D + lg * 8];
            bf16x8 a1 = *(const bf16x8*)&hbf[(size_t)ra * D + 32 + lg * 8];

            f32x4 c1[4];
#pragma unroll
            for (int nt = 0; nt < 4; ++nt) {
                f32x4 z = {0.f, 0.f, 0.f, 0.f};
                z = __builtin_amdgcn_mfma_f32_16x16x32_bf16(a0, w1f[nt][0], z, 0, 0, 0);
                z = __builtin_amdgcn_mfma_f32_16x16x32_bf16(a1, w1f[nt][1], z, 0, 0, 0);
                c1[nt] = z;
            }
#pragma unroll
            for (int nt = 0; nt < 4; ++nt)
#pragma unroll
              for (int j = 0; j < 4; ++j) {
                float v = fmaxf(c1[nt][j] + b1v[nt], 0.f);
                lds_h[wid][lg * 4 + j][nt * 16 + lr] = f2bf(v);
              }

            bf16x8 h0 = *(const bf16x8*)&lds_h[wid][lr][lg * 8];
            bf16x8 h1 = *(const bf16x8*)&lds_h[wid][lr][32 + lg * 8];

            f32x4 c2[4];
#pragma unroll
            for (int nt = 0; nt < 4; ++nt) {
                f32x4 z = {0.f, 0.f, 0.f, 0.f};
                z = __builtin_amdgcn_mfma_f32_16x16x32_bf16(h0, w2f[nt][0], z, 0, 0, 0);
                z = __builtin_amdgcn_mfma_f32_16x16x32_bf16(h1, w2f[nt][1], z, 0, 0, 0);
                c2[nt] = z;
            }

            if (!LAST) {
#pragma unroll
                for (int nt = 0; nt < 4; ++nt)
#pragma unroll
                  for (int j = 0; j < 4; ++j) {
                    int gr = m0 + lg * 4 + j;
                    if (gr < N) {
                        float v = fmaxf(c2[nt][j] + b2v[nt], 0.f);
                        xout[(size_t)gr * D + nt * 16 + lr] = f2bf(v);
                    }
                  }
            } else {
                float s0 = 0.f, s1 = 0.f, s2 = 0.f, s3 = 0.f;
#pragma unroll
                for (int nt = 0; nt < 4; ++nt) {
                    s0 = fmaf(fmaxf(c2[nt][0] + b2v[nt], 0.f), wov[nt], s0);
                    s1 = fmaf(fmaxf(c2[nt][1] + b2v[nt], 0.f), wov[nt], s1);
                    s2 = fmaf(fmaxf(c2[nt][2] + b2v[nt], 0.f), wov[nt], s2);
                    s3 = fmaf(fmaxf(c2[nt][3] + b2v[nt], 0.f), wov[nt], s3);
                }
#pragma unroll
                for (int o = 1; o < 16; o <<= 1) {
                    s0 += __shfl_xor(s0, o, 64);
                    s1 += __shfl_xor(s1, o, 64);
                    s2 += __shfl_xor(s2, o, 64);
                    s3 += __shfl_xor(s3, o, 64);
                }
                if (lr == 0) {
                    int gr = m0 + lg * 4;
                    if (gr + 0 < N) atomicAdd(&pool[batch[gr + 0]], s0);
                    if (gr + 1 < N) atomicAdd(&pool[batch[gr + 1]], s1);
                    if (gr + 2 < N) atomicAdd(&pool[batch[gr + 2]], s2);
                    if (gr + 3 < N) atomicAdd(&pool[batch[gr + 3]], s3);
                }
            }
        }
    }

    if (LAST) {
        __syncthreads();
        if (threadIdx.x < 128) {
            float v = pool[threadIdx.x];
            if (v != 0.f) atomicAdd(&out[threadIdx.x], v);
        }
    }
}

// ---------------------------------------------------------------------------
extern "C" void kernel_launch(void* const* d_in, const int* in_sizes, int n_in,
                              void* d_out, int out_size, void* d_ws, size_t ws_size,
                              hipStream_t stream) {
    const float* x     = (const float*)d_in[0];
    const int*   ei    = (const int*)d_in[1];
    const float* ea    = (const float*)d_in[2];
    const int*   batch = (const int*)d_in[3];
    const float* W1    = (const float*)d_in[4];
    const float* b1    = (const float*)d_in[5];
    const float* W2    = (const float*)d_in[6];
    const float* b2    = (const float*)d_in[7];
    const float* Wout  = (const float*)d_in[8];
    const float* bout  = (const float*)d_in[9];
    float* out = (float*)d_out;

    const int N = in_sizes[0] / D;   // 100000
    const int E = in_sizes[1] / 2;   // 1200000
    const int G = out_size;          // 128

    // ---- workspace layout ----
    char* w = (char*)d_ws;
    u16*   xbfA    = (u16*)w;              w += (size_t)N * D * sizeof(u16);
    u16*   xbfB    = (u16*)w;              w += (size_t)N * D * sizeof(u16);
    u16*   hbf     = (u16*)w;              w += (size_t)N * D * sizeof(u16);
    int*   src_csr = (int*)w;              w += (size_t)E * sizeof(int);
    int*   deg     = (int*)w;              w += (size_t)N * sizeof(int);
    int*   off     = (int*)w;              w += (size_t)N * sizeof(int);
    int*   cur     = (int*)w;              w += (size_t)N * sizeof(int);
    int*   bsum    = (int*)w;              w += 128 * sizeof(int);
    int*   boff    = (int*)w;              w += 128 * sizeof(int);
    u16*   ea_csr  = (u16*)w;              // E*D*2 bytes

    const int nScanBlocks = (N + 1023) / 1024;
    const int edgeBlocks  = (E + 255) / 256;
    const int buildBlocks = (E + 15) / 16;
    const int aggBlocks   = (N + 3) / 4;       // one wave per node

    const long long nx4 = (long long)N * D / 4;
    const int convxBlocks = (int)((nx4 + 255) / 256);

    const int ntiles    = (N + 63) / 64;       // 1563
    const int mlpBlocks = 782;

    // ---- init (out=bout, deg=0, cur=0) ----
    init_kernel<<<(N + 255) / 256, 256, 0, stream>>>(out, bout, deg, cur, N, G);

    // ---- CSR build + bf16 edge reorder + x0 bf16 convert ----
    deg_hist_kernel<<<edgeBlocks, 256, 0, stream>>>(ei, deg, E);
    scan1_kernel<<<nScanBlocks, 1024, 0, stream>>>(deg, off, bsum, N);
    scan2_kernel<<<1, 128, 0, stream>>>(bsum, boff, nScanBlocks);
    build_kernel<<<buildBlocks, 256, 0, stream>>>(ea, ei, off, boff, cur,
                                                  src_csr, ea_csr, E);
    convx_kernel<<<convxBlocks, 256, 0, stream>>>(x, xbfA, nx4);

    // ---- 3 layers: aggregate -> MFMA mlp ----
    u16* xcur = xbfA;
    u16* xnxt = xbfB;
    for (int l = 0; l < 3; ++l) {
        aggregate_kernel<<<aggBlocks, 256, 0, stream>>>(xcur, ea_csr, src_csr,
                                                        off, boff, deg, hbf, N);
        if (l < 2) {
            mlp_mfma_kernel<0><<<mlpBlocks, 256, 0, stream>>>(hbf, xnxt,
                W1 + l * D * D, b1 + l * D, W2 + l * D * D, b2 + l * D,
                batch, Wout, out, N, ntiles);
            u16* t = xcur; xcur = xnxt; xnxt = t;
        } else {
            mlp_mfma_kernel<1><<<mlpBlocks, 256, 0, stream>>>(hbf, nullptr,
                W1 + l * D * D, b1 + l * D, W2 + l * D * D, b2 + l * D,
                batch, Wout, out, N, ntiles);
        }
    }
}